// Round 4
// baseline (873.676 us; speedup 1.0000x reference)
//
#include <hip/hip_runtime.h>

// EntityAwareLSTMLayer: B=1024, T=365, DYN=32, STATIC=27, U=256 (3U=768)
// Round 8: latency-bound at 2 waves/SIMD -> go to 16 waves (4/SIMD).
//   Post-mortems: R6 (LDS ops -29%, conflicts->0) null; R7 (no global in
//   loop) -5%. True per-SIMD MfmaUtil ~14%, LDS pipe ~40%, VALU ~13% ->
//   nothing saturated => serial per-step chain exposed at occupancy 23.5%.
//   - 256 WGs x 1024 thr (16 waves, 4/SIMD): wave owns 16 units -> resident
//     frags 7hh*3 + 3x = 24 frags = 96 regs, fits the 128-reg budget.
//     Total W_hh register residency per CU unchanged (~384 KB).
//   - Chunk 7 streamed from 49 KB LDS tile; x fully pre-staged (93.4 KB);
//     A h-only dbuf (4.3 KB). LDS total 146.9 KB (= R7).
//   - 1 cell/lane: tail VALU halves; biases folded into acc init.
//   - Accept 192 A-dup reads/CU/step (LDS proven non-binding by R6).

typedef short short8 __attribute__((ext_vector_type(8)));
typedef short short4s __attribute__((ext_vector_type(4)));
typedef float f32x4 __attribute__((ext_vector_type(4)));

#define T_STEPS 365
#define UNITS   256
#define G3      768
#define KTOT    288   // 256 (h) + 32 (x)
#define MROWS   4
#define NWGS    256
#define NTHR    1024
#define HP      272   // h row stride in shorts (136 dw == 8 mod 32 -> 2-way free)
#define XROW    (T_STEPS * 32)   // 11,680 shorts per batch row
#define NRES    7     // W_hh 32-k chunks resident in registers (ks 0..6)

__device__ __forceinline__ unsigned short f2bf(float x) {
    union { float f; unsigned u; } v; v.f = x;
    return (unsigned short)((v.u + 0x7FFFu + ((v.u >> 16) & 1u)) >> 16);
}
__device__ __forceinline__ float sigmoidf_(float x) {
    return 1.0f / (1.0f + __expf(-x));
}
__device__ __forceinline__ float tanhf_(float x) {
    return 1.0f - 2.0f / (1.0f + __expf(2.0f * x));
}
// pick element qq of a f32x4 with compile-time indices only (avoid scratch)
__device__ __forceinline__ float selq(f32x4 v, int qq) {
    const float a = (qq & 1) ? v[1] : v[0];
    const float b = (qq & 1) ? v[3] : v[2];
    return (qq & 2) ? b : a;
}
__device__ __forceinline__ f32x4 MF(short8 a, short8 b, f32x4 c) {
    return __builtin_amdgcn_mfma_f32_16x16x32_bf16(a, b, c, 0, 0, 0);
}

// Wpack[k=0..287][n=0..767] -> bf16 B-fragment layout:
//   element (k,n) at wp[((k>>3)*768 + n)*8 + (k&7)]
__global__ __launch_bounds__(256) void pack_weights(
    const float* __restrict__ w_ih, const float* __restrict__ w_hh,
    unsigned short* __restrict__ wp)
{
    int idx = blockIdx.x * 256 + threadIdx.x;
    if (idx >= KTOT * G3) return;
    int k = idx / G3, n = idx - k * G3;
    float v;
    if (k < UNITS) {
        v = w_hh[k * G3 + n];
        if ((n & 255) == k) v -= 1.0f;   // subtract eye3 tile (identity added in fp32)
    } else {
        v = w_ih[(k - UNITS) * G3 + n];
    }
    wp[(((k >> 3) * G3) + n) * 8 + (k & 7)] = f2bf(v);
}

__global__ __launch_bounds__(NTHR) void lstm_mfma(
    const float* __restrict__ x_dyn,   // [1024][365][32]
    const float* __restrict__ x_sta,   // [1024][27]
    const unsigned short* __restrict__ wp,  // packed bf16 [36][768][8]
    const float* __restrict__ w_sh,    // [27][256]
    const float* __restrict__ bias,    // [768]
    const float* __restrict__ bias_s,  // [256]
    float* __restrict__ out)           // [1024][256]
{
    __shared__ unsigned short A_s[2][MROWS][HP];      //  4,352 B (h only, dbuf)
    __shared__ unsigned short xs[MROWS * XROW];       // 93,440 B (all x, bf16)
    __shared__ unsigned short Bs_s[4 * G3 * 8];       // 49,152 B (W_hh chunk 7)

    const int tid  = threadIdx.x;
    const int b0   = blockIdx.x * MROWS;
    const int lane = tid & 63;
    const int wv   = tid >> 6;          // wave 0..15, owns units wv*16..+15
    const int mm   = lane & 15;
    const int qq   = lane >> 4;

    // ---- persistent B fragments: 21 (hh ks 0..6) + 3 (ih) = 24 frags = 96 regs ----
    short8 bw[NRES][3];
    #pragma unroll
    for (int ks = 0; ks < NRES; ++ks)
        #pragma unroll
        for (int g = 0; g < 3; ++g)
            bw[ks][g] = *(const short8*)(wp +
                ((size_t)(ks * 4 + qq) * G3 + g * UNITS + wv * 16 + mm) * 8);
    short8 bwx[3];
    #pragma unroll
    for (int g = 0; g < 3; ++g)
        bwx[g] = *(const short8*)(wp +
            ((size_t)(32 + qq) * G3 + g * UNITS + wv * 16 + mm) * 8);

    // ---- stage streamed W_hh chunk 7 (k=224..255, sub-chunks 28..31) ----
    {
        const short8* src = (const short8*)(wp + (size_t)28 * G3 * 8);
        short8* dst = (short8*)Bs_s;
        for (int i = tid; i < 4 * G3; i += NTHR) dst[i] = src[i];
    }
    // ---- pre-stage ALL x for this WG's 4 batch rows (fp32 -> bf16) ----
    #pragma unroll
    for (int r = 0; r < MROWS; ++r) {
        const float4* src = (const float4*)(x_dyn + (size_t)(b0 + r) * XROW);
        short4s* dst = (short4s*)(xs + r * XROW);
        for (int i = tid; i < XROW / 4; i += NTHR) {
            const float4 v = src[i];
            short4s w;
            w.x = (short)f2bf(v.x); w.y = (short)f2bf(v.y);
            w.z = (short)f2bf(v.z); w.w = (short)f2bf(v.w);
            dst[i] = w;
        }
    }
    // zero both h buffers (h must be 0 at t=0)
    {
        int* az = (int*)A_s;
        for (int i = tid; i < 2 * MROWS * HP / 2; i += NTHR) az[i] = 0;
    }
    __syncthreads();

    // ---- cell mapping: lane (mm,qq) owns ONE cell (batch row qq, unit u) ----
    const int u = wv * 16 + mm;

    const float bf = bias[u];
    const float bo = bias[UNITS + u];
    const float bg = bias[2 * UNITS + u];

    float ig, cc = 0.0f, hp = 0.0f;
    {
        float s = bias_s[u];
        #pragma unroll
        for (int j = 0; j < 27; ++j)
            s += x_sta[(b0 + qq) * 27 + j] * w_sh[j * UNITS + u];
        ig = sigmoidf_(s);
    }

    const int arow  = (mm & 3);         // dedup: quads broadcast-read same 4 rows
    const int abase = arow * HP + qq * 8;
    const int xbase = arow * XROW + qq * 8;
    const int bsoff = (qq * G3 + wv * 16 + mm) * 8;   // streamed-B lane offset

    for (int t = 0; t < T_STEPS; ++t) {
        const int p = t & 1;
        __syncthreads();   // A[p] h complete; A[p^1] free. No vmem in flight.

        const unsigned short* Ap = &A_s[p][0][0];

        // biases pre-folded into accumulators (shortens the tail chain)
        f32x4 acf = {bf, bf, bf, bf};
        f32x4 aco = {bo, bo, bo, bo};
        f32x4 acg = {bg, bg, bg, bg};

        // x-contribution first (operands ready; overlaps A-read latency)
        {
            const short8 a = *(const short8*)(xs + xbase + t * 32);
            acf = MF(a, bwx[0], acf);
            aco = MF(a, bwx[1], aco);
            acg = MF(a, bwx[2], acg);
        }
        // k-chunks 0..6: B in registers; each A frag read once, feeds 3 MFMAs
        #pragma unroll
        for (int ks = 0; ks < NRES; ++ks) {
            const short8 a = *(const short8*)(Ap + abase + ks * 32);
            acf = MF(a, bw[ks][0], acf);
            aco = MF(a, bw[ks][1], aco);
            acg = MF(a, bw[ks][2], acg);
        }
        // k-chunk 7: B streamed from LDS (short-lived frags)
        {
            const short8 a = *(const short8*)(Ap + abase + NRES * 32);
            acf = MF(a, *(const short8*)(Bs_s + bsoff),                 acf);
            aco = MF(a, *(const short8*)(Bs_s + bsoff + UNITS * 8),     aco);
            acg = MF(a, *(const short8*)(Bs_s + bsoff + 2 * UNITS * 8), acg);
        }

        // ---- cell update: acc reg qq IS this lane's cell (no cross-lane) ----
        {
            const float h0v = hp;                    // exact fp32 identity term
            const float gfv = selq(acf, qq) + h0v;
            const float gov = selq(aco, qq) + h0v;
            const float ggv = selq(acg, qq) + h0v;
            const float f   = sigmoidf_(gfv);
            const float o   = sigmoidf_(gov);
            const float gt  = tanhf_(ggv);
            const float cn  = f * cc + ig * gt;
            cc = cn;
            const float hn  = o * tanhf_(cn);
            hp = hn;
            A_s[p ^ 1][qq][u] = f2bf(hn);            // single b16 write per cell
        }
    }

    out[(size_t)(b0 + qq) * UNITS + u] = hp;
}

extern "C" void kernel_launch(void* const* d_in, const int* in_sizes, int n_in,
                              void* d_out, int out_size, void* d_ws, size_t ws_size,
                              hipStream_t stream) {
    const float* x_dyn  = (const float*)d_in[0];
    const float* x_sta  = (const float*)d_in[1];
    const float* w_ih   = (const float*)d_in[2];
    const float* w_hh   = (const float*)d_in[3];
    const float* w_sh   = (const float*)d_in[4];
    const float* bias   = (const float*)d_in[5];
    const float* bias_s = (const float*)d_in[6];
    float* out = (float*)d_out;
    unsigned short* wp = (unsigned short*)d_ws;   // 288*768*2 = 442 KB scratch

    pack_weights<<<(KTOT * G3 + 255) / 256, 256, 0, stream>>>(w_ih, w_hh, wp);
    lstm_mfma<<<NWGS, NTHR, 0, stream>>>(x_dyn, x_sta, wp, w_sh, bias, bias_s, out);
}

// Round 5
// 771.165 us; speedup vs baseline: 1.1329x; 1.1329x over previous
//
#include <hip/hip_runtime.h>

// EntityAwareLSTMLayer: B=1024, T=365, DYN=32, STATIC=27, U=256 (3U=768)
// Round 9: clean 4-waves/SIMD retry (R8 was spill-poisoned: VGPR=64 forced
//   the 96-reg frag set to scratch -> WRITE_SIZE 110MB).
//   - __launch_bounds__(1024, 4): hard 128-reg cap, working set sized to fit:
//     NRES=6 -> 21 resident frags = 84 regs (+acc 12 +temps ~25 = ~125).
//   - W_hh chunks 6,7 streamed from 96 KB LDS tile (6 b128/wave/step).
//   - x read from GLOBAL per step (L2/L3-resident, issued at step start,
//     consumed by the LAST MFMA -> latency hidden; no cross-barrier vmem,
//     so no vmcnt-drain at the barrier). 8 f2bf cvt/lane/step is noise.
//   - LDS = 96 KB B-tile + 4.3 KB A dbuf = 100.7 KB, 1 WG/CU, 16 waves.
//   - Tripwire: if WRITE_SIZE explodes again -> spilled -> revert knobs.

typedef short short8 __attribute__((ext_vector_type(8)));
typedef float f32x4 __attribute__((ext_vector_type(4)));

#define T_STEPS 365
#define UNITS   256
#define G3      768
#define KTOT    288   // 256 (h) + 32 (x)
#define MROWS   4
#define NWGS    256
#define NTHR    1024
#define HP      272   // h row stride in shorts (136 dw == 8 mod 32 -> 2-way free)
#define NRES    6     // W_hh 32-k chunks resident in registers (ks 0..5)

__device__ __forceinline__ unsigned short f2bf(float x) {
    union { float f; unsigned u; } v; v.f = x;
    return (unsigned short)((v.u + 0x7FFFu + ((v.u >> 16) & 1u)) >> 16);
}
__device__ __forceinline__ float sigmoidf_(float x) {
    return 1.0f / (1.0f + __expf(-x));
}
__device__ __forceinline__ float tanhf_(float x) {
    return 1.0f - 2.0f / (1.0f + __expf(2.0f * x));
}
// pick element qq of a f32x4 with compile-time indices only (avoid scratch)
__device__ __forceinline__ float selq(f32x4 v, int qq) {
    const float a = (qq & 1) ? v[1] : v[0];
    const float b = (qq & 1) ? v[3] : v[2];
    return (qq & 2) ? b : a;
}
__device__ __forceinline__ f32x4 MF(short8 a, short8 b, f32x4 c) {
    return __builtin_amdgcn_mfma_f32_16x16x32_bf16(a, b, c, 0, 0, 0);
}

// Wpack[k=0..287][n=0..767] -> bf16 B-fragment layout:
//   element (k,n) at wp[((k>>3)*768 + n)*8 + (k&7)]
__global__ __launch_bounds__(256) void pack_weights(
    const float* __restrict__ w_ih, const float* __restrict__ w_hh,
    unsigned short* __restrict__ wp)
{
    int idx = blockIdx.x * 256 + threadIdx.x;
    if (idx >= KTOT * G3) return;
    int k = idx / G3, n = idx - k * G3;
    float v;
    if (k < UNITS) {
        v = w_hh[k * G3 + n];
        if ((n & 255) == k) v -= 1.0f;   // subtract eye3 tile (identity added in fp32)
    } else {
        v = w_ih[(k - UNITS) * G3 + n];
    }
    wp[(((k >> 3) * G3) + n) * 8 + (k & 7)] = f2bf(v);
}

__global__ __launch_bounds__(NTHR, 4) void lstm_mfma(
    const float* __restrict__ x_dyn,   // [1024][365][32]
    const float* __restrict__ x_sta,   // [1024][27]
    const unsigned short* __restrict__ wp,  // packed bf16 [36][768][8]
    const float* __restrict__ w_sh,    // [27][256]
    const float* __restrict__ bias,    // [768]
    const float* __restrict__ bias_s,  // [256]
    float* __restrict__ out)           // [1024][256]
{
    __shared__ unsigned short A_s[2][MROWS][HP];   //  4,352 B (h only, dbuf)
    __shared__ unsigned short Bs_s[8 * G3 * 8];    // 98,304 B (W_hh chunks 6,7)

    const int tid  = threadIdx.x;
    const int b0   = blockIdx.x * MROWS;
    const int lane = tid & 63;
    const int wv   = tid >> 6;          // wave 0..15, owns units wv*16..+15
    const int mm   = lane & 15;
    const int qq   = lane >> 4;

    // ---- persistent B fragments: 18 (hh ks 0..5) + 3 (ih) = 21 frags = 84 regs ----
    short8 bw[NRES][3];
    #pragma unroll
    for (int ks = 0; ks < NRES; ++ks)
        #pragma unroll
        for (int g = 0; g < 3; ++g)
            bw[ks][g] = *(const short8*)(wp +
                ((size_t)(ks * 4 + qq) * G3 + g * UNITS + wv * 16 + mm) * 8);
    short8 bwx[3];
    #pragma unroll
    for (int g = 0; g < 3; ++g)
        bwx[g] = *(const short8*)(wp +
            ((size_t)(32 + qq) * G3 + g * UNITS + wv * 16 + mm) * 8);

    // ---- stage streamed W_hh chunks 6,7 (k=192..255, sub-chunks 24..31) ----
    {
        const short8* src = (const short8*)(wp + (size_t)24 * G3 * 8);
        short8* dst = (short8*)Bs_s;
        for (int i = tid; i < 8 * G3; i += NTHR) dst[i] = src[i];
    }
    // zero both h buffers (h must be 0 at t=0)
    {
        int* az = (int*)A_s;
        for (int i = tid; i < 2 * MROWS * HP / 2; i += NTHR) az[i] = 0;
    }
    __syncthreads();

    // ---- cell mapping: lane (mm,qq) owns ONE cell (batch row qq, unit u) ----
    const int u = wv * 16 + mm;

    const float bf = bias[u];
    const float bo = bias[UNITS + u];
    const float bg = bias[2 * UNITS + u];

    float ig, cc = 0.0f, hps = 0.0f;
    {
        float s = bias_s[u];
        #pragma unroll
        for (int j = 0; j < 27; ++j)
            s += x_sta[(b0 + qq) * 27 + j] * w_sh[j * UNITS + u];
        ig = sigmoidf_(s);
    }

    const int arow  = (mm & 3);         // dedup: quads broadcast-read same 4 rows
    const int abase = arow * HP + qq * 8;
    // streamed-B lane offsets (chunks 6,7 -> tile halves 0,1)
    const int bs0 = (qq * G3 + wv * 16 + mm) * 8;
    const int bs1 = bs0 + 4 * G3 * 8;
    // per-lane x source: x_dyn[b0+arow][t][qq*8 .. +7]
    const float* xsrc = x_dyn + ((size_t)(b0 + arow) * T_STEPS) * 32 + qq * 8;

    for (int t = 0; t < T_STEPS; ++t) {
        const int p = t & 1;
        __syncthreads();   // A[p] h complete; A[p^1] free. No vmem in flight.

        // issue x load FIRST (independent of h; ~350cy L2/L3 latency hides
        // under the 6 register-chunk MFMA phase below)
        const float4 xa = *(const float4*)(xsrc + (size_t)t * 32);
        const float4 xb = *(const float4*)(xsrc + (size_t)t * 32 + 4);

        const unsigned short* Ap = &A_s[p][0][0];

        // biases pre-folded into accumulators (shortens the tail chain)
        f32x4 acf = {bf, bf, bf, bf};
        f32x4 aco = {bo, bo, bo, bo};
        f32x4 acg = {bg, bg, bg, bg};

        // k-chunks 0..5: B in registers; each A frag read once, feeds 3 MFMAs
        #pragma unroll
        for (int ks = 0; ks < NRES; ++ks) {
            const short8 a = *(const short8*)(Ap + abase + ks * 32);
            acf = MF(a, bw[ks][0], acf);
            aco = MF(a, bw[ks][1], aco);
            acg = MF(a, bw[ks][2], acg);
        }
        // k-chunks 6,7: B streamed from LDS (short-lived frags)
        {
            const short8 a = *(const short8*)(Ap + abase + 6 * 32);
            acf = MF(a, *(const short8*)(Bs_s + bs0),                 acf);
            aco = MF(a, *(const short8*)(Bs_s + bs0 + UNITS * 8),     aco);
            acg = MF(a, *(const short8*)(Bs_s + bs0 + 2 * UNITS * 8), acg);
        }
        {
            const short8 a = *(const short8*)(Ap + abase + 7 * 32);
            acf = MF(a, *(const short8*)(Bs_s + bs1),                 acf);
            aco = MF(a, *(const short8*)(Bs_s + bs1 + UNITS * 8),     aco);
            acg = MF(a, *(const short8*)(Bs_s + bs1 + 2 * UNITS * 8), acg);
        }
        // x-contribution LAST (loads have drained by now)
        {
            short8 a;
            a[0] = (short)f2bf(xa.x); a[1] = (short)f2bf(xa.y);
            a[2] = (short)f2bf(xa.z); a[3] = (short)f2bf(xa.w);
            a[4] = (short)f2bf(xb.x); a[5] = (short)f2bf(xb.y);
            a[6] = (short)f2bf(xb.z); a[7] = (short)f2bf(xb.w);
            acf = MF(a, bwx[0], acf);
            aco = MF(a, bwx[1], aco);
            acg = MF(a, bwx[2], acg);
        }

        // ---- cell update: acc reg qq IS this lane's cell (no cross-lane) ----
        {
            const float h0v = hps;                   // exact fp32 identity term
            const float gfv = selq(acf, qq) + h0v;
            const float gov = selq(aco, qq) + h0v;
            const float ggv = selq(acg, qq) + h0v;
            const float f   = sigmoidf_(gfv);
            const float o   = sigmoidf_(gov);
            const float gt  = tanhf_(ggv);
            const float cn  = f * cc + ig * gt;
            cc = cn;
            const float hn  = o * tanhf_(cn);
            hps = hn;
            A_s[p ^ 1][qq][u] = f2bf(hn);            // single b16 write per cell
        }
    }

    out[(size_t)(b0 + qq) * UNITS + u] = hps;
}

extern "C" void kernel_launch(void* const* d_in, const int* in_sizes, int n_in,
                              void* d_out, int out_size, void* d_ws, size_t ws_size,
                              hipStream_t stream) {
    const float* x_dyn  = (const float*)d_in[0];
    const float* x_sta  = (const float*)d_in[1];
    const float* w_ih   = (const float*)d_in[2];
    const float* w_hh   = (const float*)d_in[3];
    const float* w_sh   = (const float*)d_in[4];
    const float* bias   = (const float*)d_in[5];
    const float* bias_s = (const float*)d_in[6];
    float* out = (float*)d_out;
    unsigned short* wp = (unsigned short*)d_ws;   // 288*768*2 = 442 KB scratch

    pack_weights<<<(KTOT * G3 + 255) / 256, 256, 0, stream>>>(w_ih, w_hh, wp);
    lstm_mfma<<<NWGS, NTHR, 0, stream>>>(x_dyn, x_sta, wp, w_sh, bias, bias_s, out);
}

// Round 6
// 583.805 us; speedup vs baseline: 1.4965x; 1.3209x over previous
//
#include <hip/hip_runtime.h>

// EntityAwareLSTMLayer: B=1024, T=365, DYN=32, STATIC=27, U=256 (3U=768)
// Round 10: shave the exposed non-MFMA region of the R7 base (572us).
//   Model fix: 16x16x32 bf16 MFMA ~4.85 cy per CU (~19 cy SIMD pipe) ->
//   108 MFMA/SIMD/step ~= 2,000 cy of the 3,620-cy step = MFMA-bound 55%,
//   matching MfmaUtil 52%. Floor ~350-380us. Attack the ~1,500 cy exposed:
//   - x-MFMAs FIRST with the x-fragment prefetched during the previous
//     step's tail (xs is static) -> post-barrier MFMAs start immediately,
//     covering the h A-frag ds_read latency.
//   - bias + fp32 identity (h_prev) folded into acc init (only element qq
//     of each acc is consumed -> broadcast-fold is valid); removes 12
//     dependent adds from the serial tail, hides them under LDS waits.
//   - R9 lesson kept: stay at 8 waves x 32 units, 2 waves/SIMD, x in LDS.

typedef short short8 __attribute__((ext_vector_type(8)));
typedef short short4s __attribute__((ext_vector_type(4)));
typedef float f32x4 __attribute__((ext_vector_type(4)));

#define T_STEPS 365
#define UNITS   256
#define G3      768
#define KTOT    288   // 256 (h) + 32 (x)
#define MROWS   4
#define NWGS    256
#define HP      272   // h row stride in shorts (136 dw == 8 mod 32 -> 2-way free)
#define XROW    (T_STEPS * 32)   // 11,680 shorts per batch row
#define NREG    7     // W_hh 32-k chunks resident in registers (ks 0..6)

__device__ __forceinline__ unsigned short f2bf(float x) {
    union { float f; unsigned u; } v; v.f = x;
    return (unsigned short)((v.u + 0x7FFFu + ((v.u >> 16) & 1u)) >> 16);
}
__device__ __forceinline__ float sigmoidf_(float x) {
    return 1.0f / (1.0f + __expf(-x));
}
__device__ __forceinline__ float tanhf_(float x) {
    return 1.0f - 2.0f / (1.0f + __expf(2.0f * x));
}
// pick element qq of a f32x4 with compile-time indices only (avoid scratch)
__device__ __forceinline__ float selq(f32x4 v, int qq) {
    const float a = (qq & 1) ? v[1] : v[0];
    const float b = (qq & 1) ? v[3] : v[2];
    return (qq & 2) ? b : a;
}
__device__ __forceinline__ f32x4 MF(short8 a, short8 b, f32x4 c) {
    return __builtin_amdgcn_mfma_f32_16x16x32_bf16(a, b, c, 0, 0, 0);
}

// Wpack[k=0..287][n=0..767] -> bf16 B-fragment layout:
//   element (k,n) at wp[((k>>3)*768 + n)*8 + (k&7)]
__global__ __launch_bounds__(256) void pack_weights(
    const float* __restrict__ w_ih, const float* __restrict__ w_hh,
    unsigned short* __restrict__ wp)
{
    int idx = blockIdx.x * 256 + threadIdx.x;
    if (idx >= KTOT * G3) return;
    int k = idx / G3, n = idx - k * G3;
    float v;
    if (k < UNITS) {
        v = w_hh[k * G3 + n];
        if ((n & 255) == k) v -= 1.0f;   // subtract eye3 tile (identity added in fp32)
    } else {
        v = w_ih[(k - UNITS) * G3 + n];
    }
    wp[(((k >> 3) * G3) + n) * 8 + (k & 7)] = f2bf(v);
}

__global__ __launch_bounds__(512, 2) void lstm_mfma(
    const float* __restrict__ x_dyn,   // [1024][365][32]
    const float* __restrict__ x_sta,   // [1024][27]
    const unsigned short* __restrict__ wp,  // packed bf16 [36][768][8]
    const float* __restrict__ w_sh,    // [27][256]
    const float* __restrict__ bias,    // [768]
    const float* __restrict__ bias_s,  // [256]
    float* __restrict__ out)           // [1024][256]
{
    __shared__ unsigned short A_s[2][MROWS][HP];      //  4,352 B (h only, dbuf)
    __shared__ unsigned short xs[MROWS * XROW];       // 93,440 B (all x, bf16)
    __shared__ unsigned short Bs_s[4 * G3 * 8];       // 49,152 B (W_hh chunk 7)

    const int tid  = threadIdx.x;
    const int b0   = blockIdx.x * MROWS;
    const int lane = tid & 63;
    const int wv   = tid >> 6;          // wave 0..7, owns units wv*32..+31
    const int mm   = lane & 15;
    const int qq   = lane >> 4;

    // ---- persistent B fragments: 42 (hh ks 0..6) + 6 (ih) = 48 frags ----
    short8 bw[NREG][3][2];
    #pragma unroll
    for (int ks = 0; ks < NREG; ++ks)
        #pragma unroll
        for (int g = 0; g < 3; ++g)
            #pragma unroll
            for (int h = 0; h < 2; ++h)
                bw[ks][g][h] = *(const short8*)(wp +
                    ((size_t)(ks * 4 + qq) * G3 + g * UNITS + wv * 32 + h * 16 + mm) * 8);
    short8 bwx[3][2];
    #pragma unroll
    for (int g = 0; g < 3; ++g)
        #pragma unroll
        for (int h = 0; h < 2; ++h)
            bwx[g][h] = *(const short8*)(wp +
                ((size_t)(32 + qq) * G3 + g * UNITS + wv * 32 + h * 16 + mm) * 8);

    // ---- stage streamed W_hh chunk 7 (k=224..255, sub-chunks 28..31) ----
    {
        const short8* src = (const short8*)(wp + (size_t)28 * G3 * 8);
        short8* dst = (short8*)Bs_s;
        for (int i = tid; i < 4 * G3; i += 512) dst[i] = src[i];
    }
    // ---- pre-stage ALL x for this WG's 4 batch rows (fp32 -> bf16) ----
    #pragma unroll
    for (int r = 0; r < MROWS; ++r) {
        const float4* src = (const float4*)(x_dyn + (size_t)(b0 + r) * XROW);
        short4s* dst = (short4s*)(xs + r * XROW);
        for (int i = tid; i < XROW / 4; i += 512) {
            const float4 v = src[i];
            short4s w;
            w.x = (short)f2bf(v.x); w.y = (short)f2bf(v.y);
            w.z = (short)f2bf(v.z); w.w = (short)f2bf(v.w);
            dst[i] = w;
        }
    }
    // zero both h buffers (h must be 0 at t=0)
    {
        int* az = (int*)A_s;
        for (int i = tid; i < 2 * MROWS * HP / 2; i += 512) az[i] = 0;
    }
    __syncthreads();

    // ---- cell mapping: lane (mm,qq) owns cells (batch row qq, units u0,u1) ----
    const int u0 = wv * 32 + mm;
    const int u1 = u0 + 16;

    const float bfv[2] = { bias[u0],             bias[u1] };
    const float bov[2] = { bias[UNITS + u0],     bias[UNITS + u1] };
    const float bgv[2] = { bias[2 * UNITS + u0], bias[2 * UNITS + u1] };

    float ig[2], cc[2], hp[2];
    #pragma unroll
    for (int h = 0; h < 2; ++h) {
        const int u = h ? u1 : u0;
        float s = bias_s[u];
        #pragma unroll
        for (int j = 0; j < 27; ++j)
            s += x_sta[(b0 + qq) * 27 + j] * w_sh[j * UNITS + u];
        ig[h] = sigmoidf_(s);
        cc[h] = 0.0f; hp[h] = 0.0f;
    }

    const int arow  = (mm & 3);         // dedup: quads broadcast-read same 4 rows
    const int abase = arow * HP + qq * 8;
    const unsigned short* xp = xs + (size_t)arow * XROW + qq * 8;
    const int bs = (qq * G3 + wv * 32 + mm) * 8;   // streamed-B lane offset

    // prefetch x-fragment for t=0 (xs is static after the staging barrier)
    short8 xa = *(const short8*)(xp);

    for (int t = 0; t < T_STEPS; ++t) {
        const int p = t & 1;
        __syncthreads();   // A[p] h complete; A[p^1] free. No vmem in flight.

        const unsigned short* Ap = &A_s[p][0][0];

        // acc init = bias + fp32 identity term (h_prev of this lane's cell).
        // Only element qq of each acc is consumed -> broadcast fold is valid.
        const float if0 = bfv[0] + hp[0], if1 = bfv[1] + hp[1];
        const float io0 = bov[0] + hp[0], io1 = bov[1] + hp[1];
        const float ig0 = bgv[0] + hp[0], ig1 = bgv[1] + hp[1];
        f32x4 acf0 = {if0, if0, if0, if0}, acf1 = {if1, if1, if1, if1};
        f32x4 aco0 = {io0, io0, io0, io0}, aco1 = {io1, io1, io1, io1};
        f32x4 acg0 = {ig0, ig0, ig0, ig0}, acg1 = {ig1, ig1, ig1, ig1};

        // x-contribution FIRST: operands already in registers -> these 6
        // MFMAs issue immediately, covering the h A-frag ds_read latency.
        acf0 = MF(xa, bwx[0][0], acf0);  acf1 = MF(xa, bwx[0][1], acf1);
        aco0 = MF(xa, bwx[1][0], aco0);  aco1 = MF(xa, bwx[1][1], aco1);
        acg0 = MF(xa, bwx[2][0], acg0);  acg1 = MF(xa, bwx[2][1], acg1);

        // k-chunks 0..6: B in registers; each A frag read once, feeds 6 MFMAs
        #pragma unroll
        for (int ks = 0; ks < NREG; ++ks) {
            const short8 a = *(const short8*)(Ap + abase + ks * 32);
            acf0 = MF(a, bw[ks][0][0], acf0);  acf1 = MF(a, bw[ks][0][1], acf1);
            aco0 = MF(a, bw[ks][1][0], aco0);  aco1 = MF(a, bw[ks][1][1], aco1);
            acg0 = MF(a, bw[ks][2][0], acg0);  acg1 = MF(a, bw[ks][2][1], acg1);
        }
        // k-chunk 7: B streamed from LDS (loop-invariant; compiler may hoist)
        {
            const short8 a = *(const short8*)(Ap + abase + NREG * 32);
            acf0 = MF(a, *(const short8*)(Bs_s + bs),                        acf0);
            acf1 = MF(a, *(const short8*)(Bs_s + bs + 16 * 8),               acf1);
            aco0 = MF(a, *(const short8*)(Bs_s + bs + (UNITS) * 8),          aco0);
            aco1 = MF(a, *(const short8*)(Bs_s + bs + (UNITS + 16) * 8),     aco1);
            acg0 = MF(a, *(const short8*)(Bs_s + bs + (2 * UNITS) * 8),      acg0);
            acg1 = MF(a, *(const short8*)(Bs_s + bs + (2 * UNITS + 16) * 8), acg1);
        }

        // prefetch next step's x-fragment (hides under the tail; drained by
        // the next barrier). Clamp at the last step (read is harmless).
        {
            const int tn = (t + 1 < T_STEPS) ? t + 1 : t;
            xa = *(const short8*)(xp + (size_t)tn * 32);
        }

        // ---- cell updates: acc reg qq of each f32x4 IS this lane's cell ----
        #pragma unroll
        for (int h = 0; h < 2; ++h) {
            const float gfv = selq(h ? acf1 : acf0, qq);   // bias+identity folded
            const float gov = selq(h ? aco1 : aco0, qq);
            const float ggv = selq(h ? acg1 : acg0, qq);
            const float f   = sigmoidf_(gfv);
            const float o   = sigmoidf_(gov);
            const float gt  = tanhf_(ggv);
            const float cn  = f * cc[h] + ig[h] * gt;
            cc[h] = cn;
            const float hn  = o * tanhf_(cn);
            hp[h] = hn;
            A_s[p ^ 1][qq][h ? u1 : u0] = f2bf(hn);   // single b16 write per cell
        }
    }

    out[(size_t)(b0 + qq) * UNITS + u0] = hp[0];
    out[(size_t)(b0 + qq) * UNITS + u1] = hp[1];
}

extern "C" void kernel_launch(void* const* d_in, const int* in_sizes, int n_in,
                              void* d_out, int out_size, void* d_ws, size_t ws_size,
                              hipStream_t stream) {
    const float* x_dyn  = (const float*)d_in[0];
    const float* x_sta  = (const float*)d_in[1];
    const float* w_ih   = (const float*)d_in[2];
    const float* w_hh   = (const float*)d_in[3];
    const float* w_sh   = (const float*)d_in[4];
    const float* bias   = (const float*)d_in[5];
    const float* bias_s = (const float*)d_in[6];
    float* out = (float*)d_out;
    unsigned short* wp = (unsigned short*)d_ws;   // 288*768*2 = 442 KB scratch

    pack_weights<<<(KTOT * G3 + 255) / 256, 256, 0, stream>>>(w_ih, w_hh, wp);
    lstm_mfma<<<NWGS, 512, 0, stream>>>(x_dyn, x_sta, wp, w_sh, bias, bias_s, out);
}